// Round 2
// baseline (463.665 us; speedup 1.0000x reference)
//
#include <hip/hip_runtime.h>

#define NJ 24
#define HIDN 7
#define FEATN 6
#define PER_J 120                 // padded floats per joint in LDS
#define LDS_FLOATS (NJ * PER_J)   // 2880 floats = 11520 B

// LDS layout per joint j (base = j*120), rows padded to 8 floats:
//   [0,56)   W1[r][c] at r*8+c   (r<7, c<7)
//   [56,64)  b1[c]
//   [64,112) W2[r][c] at 64+r*8+c (r<6, c<7)
//   [112,120) b2[r]

__global__ __launch_bounds__(256)
void structure_encoder_kernel(const float* __restrict__ x,
                              const float* __restrict__ W1,
                              const float* __restrict__ b1,
                              const float* __restrict__ W2,
                              const float* __restrict__ b2,
                              float* __restrict__ out, int B)
{
    __shared__ float w[LDS_FLOATS];

    // Cooperative one-time weight staging (uniform, tiny).
    for (int idx = threadIdx.x; idx < LDS_FLOATS; idx += blockDim.x) {
        int j = idx / PER_J;
        int o = idx - j * PER_J;
        float v = 0.f;
        if (o < 56) {
            int r = o >> 3, c = o & 7;
            if (c < 7) v = W1[j * 49 + r * 7 + c];
        } else if (o < 64) {
            int c = o - 56;
            if (c < 7) v = b1[j * 7 + c];
        } else if (o < 112) {
            int t = o - 64;
            int r = t >> 3, c = t & 7;
            if (c < 7) v = W2[j * 42 + r * 7 + c];
        } else {
            int r = o - 112;
            if (r < 6) v = b2[j * 6 + r];
        }
        w[idx] = v;
    }
    __syncthreads();

    int row = blockIdx.x * blockDim.x + threadIdx.x;
    if (row >= B) return;

    // Load the 24 input floats for this row as 6 float4 (row base 96B-aligned).
    float xv[NJ];
    const float4* xp = reinterpret_cast<const float4*>(x + (size_t)row * NJ);
    #pragma unroll
    for (int q = 0; q < 6; ++q) {
        float4 t = xp[q];
        xv[q * 4 + 0] = t.x; xv[q * 4 + 1] = t.y;
        xv[q * 4 + 2] = t.z; xv[q * 4 + 3] = t.w;
    }

    float feat[NJ][FEATN];   // fully-unrolled chain -> compile-time indices -> registers
    float* orow = out + (size_t)row * (NJ * FEATN);

    constexpr int parents[NJ] = {-1,0,0,0,1,2,3,4,5,6,7,8,9,9,9,12,13,14,16,17,18,19,20,21};

    #pragma unroll
    for (int j = 0; j < NJ; ++j) {
        const float* wj = &w[j * PER_J];

        float inp[HIDN];
        inp[0] = xv[j];
        const int p = parents[j];
        #pragma unroll
        for (int c = 0; c < FEATN; ++c)
            inp[1 + c] = (p < 0) ? 0.f : feat[p][c];

        float h[HIDN];
        #pragma unroll
        for (int r = 0; r < HIDN; ++r) {
            const float* wr = wj + r * 8;
            float acc = wj[56 + r];                 // b1[r]
            #pragma unroll
            for (int c = 0; c < HIDN; ++c)
                acc = fmaf(wr[c], inp[c], acc);
            h[r] = fmaxf(acc, 0.f);
        }

        #pragma unroll
        for (int r = 0; r < FEATN; ++r) {
            const float* wr = wj + 64 + r * 8;
            float acc = wj[112 + r];                // b2[r]
            #pragma unroll
            for (int c = 0; c < HIDN; ++c)
                acc = fmaf(wr[c], h[c], acc);
            feat[j][r] = fmaxf(acc, 0.f);
        }

        // Store pairs of joints: 12 floats starting at (j-1)*6, 16B-aligned.
        if (j & 1) {
            float4* dst = reinterpret_cast<float4*>(orow + (j - 1) * FEATN);
            float4 v0 = make_float4(feat[j-1][0], feat[j-1][1], feat[j-1][2], feat[j-1][3]);
            float4 v1 = make_float4(feat[j-1][4], feat[j-1][5], feat[j][0],   feat[j][1]);
            float4 v2 = make_float4(feat[j][2],   feat[j][3],   feat[j][4],   feat[j][5]);
            dst[0] = v0; dst[1] = v1; dst[2] = v2;
        }
    }
}

extern "C" void kernel_launch(void* const* d_in, const int* in_sizes, int n_in,
                              void* d_out, int out_size, void* d_ws, size_t ws_size,
                              hipStream_t stream) {
    const float* x  = (const float*)d_in[0];
    const float* W1 = (const float*)d_in[1];
    const float* b1 = (const float*)d_in[2];
    const float* W2 = (const float*)d_in[3];
    const float* b2 = (const float*)d_in[4];
    float* out = (float*)d_out;

    const int B = in_sizes[0] / NJ;
    const int block = 256;
    const int grid = (B + block - 1) / block;
    structure_encoder_kernel<<<grid, block, 0, stream>>>(x, W1, b1, W2, b2, out, B);
}